// Round 6
// baseline (287.099 us; speedup 1.0000x reference)
//
#include <hip/hip_runtime.h>
#include <hip/hip_bf16.h>
#include <hip/hip_fp16.h>

// ---------------- problem constants ----------------
#define BATCH 256
#define NEXP 200000
#define DS 96
#define DA 32
#define DIM 128
#define NCHUNK 32                     // atoms per k_compact chunk (acc[4][2] = 32 AGPR)
#define CPB 5                         // chunks per block, double-buffered staging
#define CGRID (NEXP / (NCHUNK * CPB)) // 1250 blocks
#define PREP_BLK 3125                 // k_prep: 64 atoms/block
#define SAMPLE_N 16384
#define SAMPLE_STRIDE 12              // 12*16383 = 196596 < 200000
#define SCHUNK 32                     // atoms per k_sample block
#define SBLK (SAMPLE_N / SCHUNK)      // 512
#define SAMPLE_TARGET 64              // ~64/16384 quantile -> ~780 full candidates
#define MARGIN_BINS 4                 // +0.25 in d safety margin
#define TAU_BINS 2048
#define TAU_SCALE 16.0f               // bin = floor(d * 16), covers d < 128
#define CAND_MAX 2048
#define STAGE_MAX 1536                // ~6x expected ~250 candidates per 160-atom block
#define CNT_PAD 16                    // one counter per 64B cache line
#define NGROUP 32                     // block groups (contention spreading)
#define GSLOTS 128                    // slots per (row,group); expected ~56
#define HBINS 512                     // k_cost selection histogram bins
#define RBW 441.94173824159216        // 5.0*1000/sqrt(128)

static __device__ __forceinline__ float target_w() { return (float)(1.0 / 1000.0 - 1e-6); }

typedef short short8v __attribute__((ext_vector_type(8)));
typedef float f32x4 __attribute__((ext_vector_type(4)));

// ws layout (bytes)
#define OFF_EBF   0                   // ushort [NEXP*DIM]            = 51,200,000
#define OFF_E2    51200000            // float  [NEXP]                =    800,000
#define OFF_SD2   52000000            // fp16 [BATCH][SAMPLE_N]       =  8,388,608
#define OFF_ABF   60388608            // ushort [BATCH*DIM]           =     65,536
#define OFF_B2    60454144            // float  [BATCH]               =      1,024
#define OFF_THR   60455168            // float  [BATCH]               =      1,024
#define OFF_CNT2  60456192            // int [BATCH*NGROUP*CNT_PAD]   =    524,288
#define OFF_CAND2 60980480            // float [BATCH*NGROUP*GSLOTS]  =  4,194,304
#define WS_NEEDED 65174784

__device__ __forceinline__ unsigned short f2bf(float x) {
    __hip_bfloat16 h = __float2bfloat16(x);
    return __builtin_bit_cast(unsigned short, h);
}

// async 16B global -> LDS (wave-uniform LDS base; HW scatters lane i at base+i*16)
__device__ __forceinline__ void load_lds16(const void* g, void* l) {
    __builtin_amdgcn_global_load_lds(
        (const __attribute__((address_space(1))) unsigned int*)g,
        (__attribute__((address_space(3))) unsigned int*)l, 16, 0, 0);
}

// ---------------- K1: normalize experts -> bf16 + e2; blocks<256 also do agent prep ----------------
__global__ __launch_bounds__(256) void k_prep(const float* __restrict__ experts,
                                              const float* __restrict__ stdv,
                                              const float* __restrict__ state,
                                              const float* __restrict__ action,
                                              unsigned short* __restrict__ ebf,
                                              float* __restrict__ e2g,
                                              unsigned short* __restrict__ agent_bf16,
                                              float* __restrict__ b2,
                                              int* __restrict__ cnt2) {
    __shared__ float rstdl[DIM];
    __shared__ float sq[64 * 33];     // padded stride 33 -> conflict-free reduce
    int t = threadIdx.x, blk = blockIdx.x;
    int lane = t & 63, wave = t >> 6;
    if (t < DIM) rstdl[t] = 1.0f / stdv[t];
    __syncthreads();
    const float4* e4 = reinterpret_cast<const float4*>(experts) + (size_t)blk * 2048;
    ushort4* o4 = reinterpret_cast<ushort4*>(ebf) + (size_t)blk * 2048;
#pragma unroll
    for (int j = 0; j < 8; ++j) {
        int i4 = t + 256 * j;                 // < 2048
        float4 v = e4[i4];
        int al = i4 >> 5, c32 = i4 & 31;
        int dbase = c32 * 4;
        float n0 = v.x * rstdl[dbase + 0];
        float n1 = v.y * rstdl[dbase + 1];
        float n2 = v.z * rstdl[dbase + 2];
        float n3 = v.w * rstdl[dbase + 3];
        sq[al * 33 + c32] = n0 * n0 + n1 * n1 + n2 * n2 + n3 * n3;
        ushort4 h; h.x = f2bf(n0); h.y = f2bf(n1); h.z = f2bf(n2); h.w = f2bf(n3);
        o4[i4] = h;
    }
    __syncthreads();
    if (t < 64) {
        float s = 0.f;
#pragma unroll
        for (int i = 0; i < 32; ++i) s += sq[t * 33 + i];
        e2g[blk * 64 + t] = s;
    }
    // ---- folded k_agent: blocks < BATCH also prep agent row `blk` ----
    if (blk < BATCH) {
        __syncthreads();              // sq reads (e2 reduce) done before reuse
        float rbb = 0.f;
        if (t < DIM) {
            float raw = (t < DS) ? state[blk * DS + t] : action[blk * DA + (t - DS)];
            float bb = raw * rstdl[t];
            agent_bf16[blk * DIM + t] = f2bf(bb);
            rbb = bb * bb;
        }
        if (t < NGROUP) cnt2[(blk * NGROUP + t) * CNT_PAD] = 0;
#pragma unroll
        for (int o = 32; o >= 1; o >>= 1) rbb += __shfl_xor(rbb, o, 64);
        if (lane == 0) sq[wave] = rbb;
        __syncthreads();
        if (t == 0) b2[blk] = sq[0] + sq[1] + sq[2] + sq[3];
    }
}

// ---------------- K2: sampled GEMM -> sd2 fp16 ----------------
__global__ __launch_bounds__(256) void k_sample(const unsigned short* __restrict__ ebf,
                                                const float* __restrict__ e2g,
                                                const unsigned short* __restrict__ agent_bf16,
                                                const float* __restrict__ b2,
                                                _Float16* __restrict__ sd2) {
    __shared__ unsigned short elds[SCHUNK * DIM];   // 8 KB, xor-swizzled chunks
    __shared__ float e2l[SCHUNK];
    __shared__ float b2l[BATCH];

    int t = threadIdx.x, ci = blockIdx.x;
    int lane = t & 63, wave = t >> 6, quad = lane >> 4, lm = lane & 15;
    b2l[t] = b2[t];
    if (t < SCHUNK) e2l[t] = e2g[SAMPLE_STRIDE * (ci * SCHUNK + t)];

    // async staging: wave covers 8 atoms (2 instrs x 1KB)
    {
        const char* gebf = (const char*)ebf;
        char* lbase = (char*)elds + wave * 2048;
#pragma unroll
        for (int q = 0; q < 2; ++q) {
            int aloc = wave * 8 + q * 4 + (lane >> 4);
            int atomg = SAMPLE_STRIDE * (ci * SCHUNK + aloc);
            int ch = (lane & 15) ^ (aloc & 15);
            load_lds16(gebf + (size_t)atomg * 256 + ch * 16, lbase + q * 1024);
        }
    }

    short8v afrag[4][4];
#pragma unroll
    for (int mt = 0; mt < 4; ++mt)
#pragma unroll
        for (int kk = 0; kk < 4; ++kk) {
            int row = wave * 64 + mt * 16 + lm;
            const uint4* p = reinterpret_cast<const uint4*>(agent_bf16 + row * DIM + kk * 32 + quad * 8);
            afrag[mt][kk] = __builtin_bit_cast(short8v, *p);
        }
    __syncthreads();   // drains vmcnt -> LDS staging complete

    f32x4 zero4 = {0.f, 0.f, 0.f, 0.f};
    f32x4 acc[4][2];
#pragma unroll
    for (int mt = 0; mt < 4; ++mt)
#pragma unroll
        for (int nt = 0; nt < 2; ++nt) acc[mt][nt] = zero4;
#pragma unroll
    for (int kk = 0; kk < 4; ++kk) {
        short8v bfrag[2];
#pragma unroll
        for (int nt = 0; nt < 2; ++nt) {
            int a = nt * 16 + lm;
            int ch = (kk * 4 + quad) ^ (a & 15);
            const uint4* p = reinterpret_cast<const uint4*>((const char*)elds + a * 256 + ch * 16);
            bfrag[nt] = __builtin_bit_cast(short8v, *p);
        }
#pragma unroll
        for (int mt = 0; mt < 4; ++mt)
#pragma unroll
            for (int nt = 0; nt < 2; ++nt)
                acc[mt][nt] = __builtin_amdgcn_mfma_f32_16x16x32_bf16(afrag[mt][kk], bfrag[nt], acc[mt][nt], 0, 0, 0);
    }

#pragma unroll
    for (int mt = 0; mt < 4; ++mt)
#pragma unroll
        for (int nt = 0; nt < 2; ++nt) {
            int atoml = nt * 16 + lm;
            float e2v = e2l[atoml];
#pragma unroll
            for (int r = 0; r < 4; ++r) {
                int row = wave * 64 + mt * 16 + quad * 4 + r;
                float d2 = b2l[row] + fmaf(-2.0f, acc[mt][nt][r], e2v);
                sd2[(size_t)row * SAMPLE_N + ci * SCHUNK + atoml] = (_Float16)d2;
            }
        }
}

// ---------------- K3: per-row tau from sample ----------------
__global__ __launch_bounds__(256) void k_tau(const _Float16* __restrict__ sd2,
                                             const float* __restrict__ b2,
                                             float* __restrict__ thr) {
    __shared__ unsigned int hist[TAU_BINS];
    __shared__ unsigned int part[256];
    int t = threadIdx.x, row = blockIdx.x;
    for (int i = t; i < TAU_BINS; i += 256) hist[i] = 0;
    __syncthreads();
    const uint4* r4 = reinterpret_cast<const uint4*>(sd2 + (size_t)row * SAMPLE_N);  // 2048 uint4
#pragma unroll
    for (int it = 0; it < 8; ++it) {
        uint4 v = r4[t + 256 * it];
        unsigned int wv[4] = {v.x, v.y, v.z, v.w};
#pragma unroll
        for (int q = 0; q < 4; ++q)
#pragma unroll
            for (int hh = 0; hh < 2; ++hh) {
                unsigned short bits = (unsigned short)((wv[q] >> (16 * hh)) & 0xffffu);
                float d2f = (float)__builtin_bit_cast(_Float16, bits);
                int bn = (int)(sqrtf(fmaxf(d2f, 0.f)) * TAU_SCALE);
                bn = bn < 0 ? 0 : (bn > TAU_BINS - 1 ? TAU_BINS - 1 : bn);
                atomicAdd(&hist[bn], 1u);
            }
    }
    __syncthreads();
    unsigned int s = 0;
#pragma unroll
    for (int i = 0; i < 8; ++i) s += hist[t * 8 + i];
    part[t] = s;
    __syncthreads();
    if (t == 0) {
        unsigned int cum = 0;
        int B = TAU_BINS - 1;
        for (int c = 0; c < 256; ++c) {
            if (cum + part[c] >= SAMPLE_TARGET) {
                unsigned int cc = cum;
                for (int i = 0; i < 8; ++i) {
                    cc += hist[c * 8 + i];
                    if (cc >= SAMPLE_TARGET) { B = c * 8 + i; break; }
                }
                break;
            }
            cum += part[c];
        }
        int tb = B + MARGIN_BINS;
        if (tb > TAU_BINS - 1) tb = TAU_BINS - 1;
        float td = (float)(tb + 1) * (1.0f / TAU_SCALE);
        thr[row] = td * td - b2[row];   // compare:  e2 - 2*dot <= thr
    }
}

// ---------------- K4: 5-chunk double-buffered GEMM + once-per-block compaction ----------------
// Round-6: CPB=5 x NCHUNK=32 = 160 atoms/block, 1250 blocks. The round-5 counters
// showed WRITE_SIZE 14.5MB (useful output ~0.8MB): the per-block epilogue's
// cnt2 atomic-RMW dirties ~100 64B lines x 3125 blocks. Epilogue now runs once
// per 160 atoms (1250x total, was 3125x): RMW latency and write traffic /2.5.
// Only chunk 0's staging drain is exposed; chunks 1-4 prefetch under MFMA+push.
// #pragma unroll 1 on the chunk loop keeps the compiler from CSE-hoisting the
// 16 afrag loads into 64 extra VGPRs (round-3's band blowout): stays ~96 unified
// regs -> 4-wave band eligible. LDS ~34KB -> 4 blocks/CU.
__global__ __launch_bounds__(256, 4) void k_compact(const unsigned short* __restrict__ ebf,
                                                    const float* __restrict__ e2g,
                                                    const unsigned short* __restrict__ agent_bf16,
                                                    const float* __restrict__ thr,
                                                    const float* __restrict__ b2,
                                                    int* __restrict__ cnt2,
                                                    float* __restrict__ cand2) {
    __shared__ unsigned short elds[2][NCHUNK * DIM];    // 2 x 8 KB, xor-swizzled
    __shared__ float e2l[2][NCHUNK];
    __shared__ float thrl[BATCH], b2l[BATCH];
    __shared__ unsigned int stage_pk[STAGE_MAX];        // row routing
    __shared__ float stage_d2[STAGE_MAX];
    __shared__ int rowcnt[BATCH], rowbase[BATCH], rowoff[BATCH];
    __shared__ int nlds;

    int t = threadIdx.x, blk = blockIdx.x;
    int grp = blk % NGROUP;                             // spread concurrent blocks
    int lane = t & 63, wave = t >> 6, quad = lane >> 4, lm = lane & 15;
    thrl[t] = thr[t];
    b2l[t] = b2[t];
    if (t < NCHUNK) e2l[0][t] = e2g[(blk * CPB) * NCHUNK + t];
    rowcnt[t] = 0; rowoff[t] = 0;
    if (t == 0) nlds = 0;

    // prologue: stage chunk 0 into buffer 0 (wave covers 8 atoms, 2 instrs x 1KB)
    {
        const char* gbase = (const char*)ebf + (size_t)(blk * CPB) * NCHUNK * 256;
        char* lbase = (char*)elds[0] + wave * 2048;
#pragma unroll
        for (int q = 0; q < 2; ++q) {
            int aloc = wave * 8 + q * 4 + (lane >> 4);
            int ch = (lane & 15) ^ (aloc & 15);
            load_lds16(gbase + (size_t)aloc * 256 + ch * 16, lbase + q * 1024);
        }
    }
    __syncthreads();   // drains vmcnt -> chunk0 + LDS scalars ready

#pragma unroll 1
    for (int c = 0; c < CPB; ++c) {
        int cur = c & 1;

        // issue next chunk's staging FIRST (in flight across this chunk's MFMA)
        if (c + 1 < CPB) {
            int nk = blk * CPB + c + 1;
            const char* gbase = (const char*)ebf + (size_t)nk * NCHUNK * 256;
            char* lbase = (char*)elds[cur ^ 1] + wave * 2048;
#pragma unroll
            for (int q = 0; q < 2; ++q) {
                int aloc = wave * 8 + q * 4 + (lane >> 4);
                int ch = (lane & 15) ^ (aloc & 15);
                load_lds16(gbase + (size_t)aloc * 256 + ch * 16, lbase + q * 1024);
            }
            if (t < NCHUNK) e2l[cur ^ 1][t] = e2g[nk * NCHUNK + t];
        }

        // MFMA on elds[cur]
        f32x4 zero4 = {0.f, 0.f, 0.f, 0.f};
        f32x4 acc[4][2];
#pragma unroll
        for (int mt = 0; mt < 4; ++mt)
#pragma unroll
            for (int nt = 0; nt < 2; ++nt) acc[mt][nt] = zero4;

#pragma unroll
        for (int kk = 0; kk < 4; ++kk) {
            short8v afrag[4];
#pragma unroll
            for (int mt = 0; mt < 4; ++mt) {
                int row = wave * 64 + mt * 16 + lm;
                const uint4* p = reinterpret_cast<const uint4*>(agent_bf16 + row * DIM + kk * 32 + quad * 8);
                afrag[mt] = __builtin_bit_cast(short8v, *p);
            }
#pragma unroll
            for (int nt = 0; nt < 2; ++nt) {
                int a = nt * 16 + lm;
                int ch = (kk * 4 + quad) ^ (a & 15);
                const uint4* p = reinterpret_cast<const uint4*>((const char*)elds[cur] + a * 256 + ch * 16);
                short8v bfrag = __builtin_bit_cast(short8v, *p);
#pragma unroll
                for (int mt = 0; mt < 4; ++mt)
                    acc[mt][nt] = __builtin_amdgcn_mfma_f32_16x16x32_bf16(afrag[mt], bfrag, acc[mt][nt], 0, 0, 0);
            }
        }

        // push passing (row, d2) into the block-wide LDS stage (accumulates over chunks)
#pragma unroll
        for (int mt = 0; mt < 4; ++mt)
#pragma unroll
            for (int nt = 0; nt < 2; ++nt) {
                int atoml = nt * 16 + lm;
                float e2v = e2l[cur][atoml];
#pragma unroll
                for (int r = 0; r < 4; ++r) {
                    int row = wave * 64 + mt * 16 + quad * 4 + r;
                    float lhs = fmaf(-2.0f, acc[mt][nt][r], e2v);
                    if (lhs <= thrl[row]) {
                        int p = atomicAdd(&nlds, 1);
                        if (p < STAGE_MAX) {
                            stage_pk[p] = (unsigned int)row;
                            stage_d2[p] = b2l[row] + lhs;
                            atomicAdd(&rowcnt[row], 1);
                        }
                    }
                }
            }

        __syncthreads();   // next buffer staged; stage arrays coherent
    }

    // epilogue (once per block = once per 160 atoms)
    int n = nlds < STAGE_MAX ? nlds : STAGE_MAX;

    int rc = rowcnt[t];
    if (rc > 0) rowbase[t] = atomicAdd(&cnt2[(t * NGROUP + grp) * CNT_PAD], rc);
    __syncthreads();

    for (int i = t; i < n; i += 256) {
        int row = (int)(stage_pk[i] & 255u);
        int pos = rowbase[row] + atomicAdd(&rowoff[row], 1);
        if (pos < GSLOTS) cand2[(row * NGROUP + grp) * GSLOTS + pos] = stage_d2[i];
    }
}

// ---------------- K5: selection-based greedy cost (uniform weights; no sort) ----------------
__global__ __launch_bounds__(256) void k_cost(const float* __restrict__ cand2,
                                              const int* __restrict__ cnt2,
                                              const float* __restrict__ weights,
                                              const float* __restrict__ thr,
                                              const float* __restrict__ b2,
                                              float* __restrict__ out) {
    __shared__ float cdl[CAND_MAX];
    __shared__ unsigned int hist[HBINS];
    __shared__ unsigned int part[256];
    __shared__ int gcnt[NGROUP], goff[NGROUP + 1];
    __shared__ float bb[64];
    __shared__ float wred[4];
    __shared__ unsigned int wtot[4];
    __shared__ int nb;
    __shared__ int Bs, c0s;
    __shared__ float dmin2S;

    int t = threadIdx.x, row = blockIdx.x;
    int lane = t & 63, wave = t >> 6;
    for (int i = t; i < HBINS; i += 256) hist[i] = 0;
    if (t < NGROUP) {
        int nn = cnt2[(row * NGROUP + t) * CNT_PAD];
        gcnt[t] = nn < GSLOTS ? nn : GSLOTS;
    }
    if (t == 0) nb = 0;
    __syncthreads();
    if (t == 0) {
        int s = 0;
        for (int g = 0; g < NGROUP; ++g) { goff[g] = s; s += gcnt[g]; }
        goff[NGROUP] = s < CAND_MAX ? s : CAND_MAX;
    }
    __syncthreads();
    int nc = goff[NGROUP];
    float tau2 = thr[row] + b2[row];           // all candidates have d2 <= tau2

    // copy candidate d2 values into LDS (wave per group, round-robin)
    {
        for (int g = wave; g < NGROUP; g += 4) {
            int n = gcnt[g], base = goff[g];
            const float* src = cand2 + (row * NGROUP + g) * GSLOTS;
            for (int i = lane; i < n; i += 64) {
                int slot = base + i;
                if (slot < CAND_MAX) cdl[slot] = src[i];
            }
        }
    }
    __syncthreads();

    // block min of d2 (shuffle + tiny LDS)
    float mn = tau2;
    for (int i = t; i < nc; i += 256) mn = fminf(mn, cdl[i]);
#pragma unroll
    for (int o = 32; o >= 1; o >>= 1) mn = fminf(mn, __shfl_xor(mn, o, 64));
    if (lane == 0) wred[wave] = mn;
    __syncthreads();
    if (t == 0) dmin2S = fminf(fminf(wred[0], wred[1]), fminf(wred[2], wred[3]));
    __syncthreads();
    float dmin2 = dmin2S;
    float denom = tau2 - dmin2;
    float binscale = (float)HBINS / fmaxf(denom, 1e-12f);

    // count histogram over [dmin2, tau2] (native int LDS atomics, spread bins)
    for (int i = t; i < nc; i += 256) {
        int bn = (int)((cdl[i] - dmin2) * binscale);
        bn = bn < 0 ? 0 : (bn > HBINS - 1 ? HBINS - 1 : bn);
        atomicAdd(&hist[bn], 1u);
    }
    __syncthreads();

    // two-level parallel prefix: part[t] = hist[2t]+hist[2t+1]; shuffle scan per wave
    unsigned int pv = hist[2 * t] + hist[2 * t + 1];
    part[t] = pv;
    unsigned int inc = pv;
#pragma unroll
    for (int o = 1; o < 64; o <<= 1) {
        unsigned int up = __shfl_up(inc, o, 64);
        if (lane >= o) inc += up;
    }
    if (lane == 63) wtot[wave] = inc;
    __syncthreads();
    unsigned int woffs = 0;
    for (int w = 0; w < wave; ++w) woffs += wtot[w];
    unsigned int incl = inc + woffs;           // inclusive cum over pairs
    unsigned int before = incl - pv;           // cum before this pair
    // locate rank-200 bin (unique thread)
    if (before < 200u && incl >= 200u) {
        unsigned int h0 = hist[2 * t];
        if (before + h0 >= 200u) { Bs = 2 * t; c0s = (int)before; }
        else { Bs = 2 * t + 1; c0s = (int)(before + h0); }
    }
    __syncthreads();
    int B = Bs, c0 = c0s;

    // per-thread: sum d for bins < B; compact boundary bin (int atomic, tiny count)
    float sloc = 0.f;
    for (int i = t; i < nc; i += 256) {
        float d2 = cdl[i];
        int bn = (int)((d2 - dmin2) * binscale);
        bn = bn < 0 ? 0 : (bn > HBINS - 1 ? HBINS - 1 : bn);
        if (bn < B) sloc += sqrtf(fmaxf(d2, 1e-12f));
        else if (bn == B) {
            int p = atomicAdd(&nb, 1);
            if (p < 64) bb[p] = sqrtf(fmaxf(d2, 1e-12f));
        }
    }
#pragma unroll
    for (int o = 32; o >= 1; o >>= 1) sloc += __shfl_xor(sloc, o, 64);
    if (lane == 0) wred[wave] = sloc;
    __syncthreads();

    if (t == 0) {
        float s0 = wred[0] + wred[1] + wred[2] + wred[3];
        int m = nb < 64 ? nb : 64;
        // insertion sort ascending (m is tiny)
        for (int i = 1; i < m; ++i) {
            float v = bb[i]; int j = i - 1;
            while (j >= 0 && bb[j] > v) { bb[j + 1] = bb[j]; --j; }
            bb[j + 1] = v;
        }
        int need = 200 - c0;            // >= 1 by construction
        if (need > m) need = m;         // paranoia guard
        float s199 = s0;                // ranks 0..c0-1
        for (int i = 0; i < need - 1; ++i) s199 += bb[i];   // ranks c0..198
        float d200 = bb[need - 1];      // rank 199
        float w0 = weights[0];
        float cumw = 0.f;               // replicate reference's sequential fp32 cumsum
        for (int i = 0; i < 199; ++i) cumw += w0;
        float TGT = target_w();
        float cost = w0 * s199 + (TGT - cumw) * d200;
        out[row] = 5.0f * expf(-(float)RBW * cost);
    }
}

// ---------------- launch ----------------
extern "C" void kernel_launch(void* const* d_in, const int* in_sizes, int n_in,
                              void* d_out, int out_size, void* d_ws, size_t ws_size,
                              hipStream_t stream) {
    const float* state   = (const float*)d_in[0];
    const float* action  = (const float*)d_in[1];
    const float* experts = (const float*)d_in[2];
    const float* weights = (const float*)d_in[3];
    const float* stdv    = (const float*)d_in[5];
    float* out = (float*)d_out;

    if (ws_size < (size_t)WS_NEEDED) return;

    char* ws = (char*)d_ws;
    unsigned short* ebf        = (unsigned short*)(ws + OFF_EBF);
    float* e2g                 = (float*)(ws + OFF_E2);
    _Float16* sd2              = (_Float16*)(ws + OFF_SD2);
    unsigned short* agent_bf16 = (unsigned short*)(ws + OFF_ABF);
    float* b2                  = (float*)(ws + OFF_B2);
    float* thr                 = (float*)(ws + OFF_THR);
    int* cnt2                  = (int*)(ws + OFF_CNT2);
    float* cand2               = (float*)(ws + OFF_CAND2);

    k_prep<<<PREP_BLK, 256, 0, stream>>>(experts, stdv, state, action, ebf, e2g, agent_bf16, b2, cnt2);
    k_sample<<<SBLK, 256, 0, stream>>>(ebf, e2g, agent_bf16, b2, sd2);
    k_tau<<<BATCH, 256, 0, stream>>>(sd2, b2, thr);
    k_compact<<<CGRID, 256, 0, stream>>>(ebf, e2g, agent_bf16, thr, b2, cnt2, cand2);
    k_cost<<<BATCH, 256, 0, stream>>>(cand2, cnt2, weights, thr, b2, out);
}

// Round 8
// 240.034 us; speedup vs baseline: 1.1961x; 1.1961x over previous
//
#include <hip/hip_runtime.h>
#include <hip/hip_bf16.h>
#include <hip/hip_fp16.h>

// ---------------- problem constants ----------------
#define BATCH 256
#define NEXP 200000
#define DS 96
#define DA 32
#define DIM 128
#define NCHUNK 64                     // atoms per k_compact block
#define NBLK (NEXP / NCHUNK)          // 3125
#define PREP_BLK 3125                 // k_prep: 64 atoms/block
#define SAMPLE_N 16384
#define SAMPLE_STRIDE 12              // 12*16383 = 196596 < 200000
#define SCHUNK 32                     // atoms per k_sample block
#define SBLK (SAMPLE_N / SCHUNK)      // 512
#define SAMPLE_TARGET 64              // ~64/16384 quantile -> ~780 full candidates
#define MARGIN_BINS 4                 // +0.25 in d safety margin
#define TAU_BINS 2048
#define TAU_SCALE 16.0f               // bin = floor(d * 16), covers d < 128
#define CAND_MAX 2048
#define STAGE_W 256                   // per-wave stage slots (expect ~25/wave)
#define CNT_PAD 16                    // one counter per 64B cache line
#define NGROUP 32                     // block groups (contention spreading)
#define GSLOTS 128                    // slots per (row,group); expected ~25
#define HBINS 512                     // k_cost selection histogram bins
#define RBW 441.94173824159216        // 5.0*1000/sqrt(128)

static __device__ __forceinline__ float target_w() { return (float)(1.0 / 1000.0 - 1e-6); }

typedef short short8v __attribute__((ext_vector_type(8)));
typedef float f32x4 __attribute__((ext_vector_type(4)));

// ws layout (bytes)
#define OFF_EBF   0                   // ushort [NEXP*DIM]            = 51,200,000
#define OFF_E2    51200000            // float  [NEXP]                =    800,000
#define OFF_SD2   52000000            // fp16 [BATCH][SAMPLE_N]       =  8,388,608
#define OFF_ABF   60388608            // ushort [BATCH*DIM]           =     65,536
#define OFF_B2    60454144            // float  [BATCH]               =      1,024
#define OFF_THR   60455168            // float  [BATCH]               =      1,024
#define OFF_CNT2  60456192            // int [BATCH*NGROUP*CNT_PAD]   =    524,288
#define OFF_CAND2 60980480            // float [BATCH*NGROUP*GSLOTS]  =  4,194,304
#define WS_NEEDED 65174784

__device__ __forceinline__ unsigned short f2bf(float x) {
    __hip_bfloat16 h = __float2bfloat16(x);
    return __builtin_bit_cast(unsigned short, h);
}

// async 16B global -> LDS (wave-uniform LDS base; HW scatters lane i at base+i*16)
__device__ __forceinline__ void load_lds16(const void* g, void* l) {
    __builtin_amdgcn_global_load_lds(
        (const __attribute__((address_space(1))) unsigned int*)g,
        (__attribute__((address_space(3))) unsigned int*)l, 16, 0, 0);
}

// ---------------- K1: normalize experts -> bf16 + e2; blocks<256 also do agent prep ----------------
__global__ __launch_bounds__(256) void k_prep(const float* __restrict__ experts,
                                              const float* __restrict__ stdv,
                                              const float* __restrict__ state,
                                              const float* __restrict__ action,
                                              unsigned short* __restrict__ ebf,
                                              float* __restrict__ e2g,
                                              unsigned short* __restrict__ agent_bf16,
                                              float* __restrict__ b2,
                                              int* __restrict__ cnt2) {
    __shared__ float rstdl[DIM];
    __shared__ float sq[64 * 33];     // padded stride 33 -> conflict-free reduce
    int t = threadIdx.x, blk = blockIdx.x;
    int lane = t & 63, wave = t >> 6;
    if (t < DIM) rstdl[t] = 1.0f / stdv[t];
    __syncthreads();
    const float4* e4 = reinterpret_cast<const float4*>(experts) + (size_t)blk * 2048;
    ushort4* o4 = reinterpret_cast<ushort4*>(ebf) + (size_t)blk * 2048;
#pragma unroll
    for (int j = 0; j < 8; ++j) {
        int i4 = t + 256 * j;                 // < 2048
        float4 v = e4[i4];
        int al = i4 >> 5, c32 = i4 & 31;
        int dbase = c32 * 4;
        float n0 = v.x * rstdl[dbase + 0];
        float n1 = v.y * rstdl[dbase + 1];
        float n2 = v.z * rstdl[dbase + 2];
        float n3 = v.w * rstdl[dbase + 3];
        sq[al * 33 + c32] = n0 * n0 + n1 * n1 + n2 * n2 + n3 * n3;
        ushort4 h; h.x = f2bf(n0); h.y = f2bf(n1); h.z = f2bf(n2); h.w = f2bf(n3);
        o4[i4] = h;
    }
    __syncthreads();
    if (t < 64) {
        float s = 0.f;
#pragma unroll
        for (int i = 0; i < 32; ++i) s += sq[t * 33 + i];
        e2g[blk * 64 + t] = s;
    }
    // ---- folded k_agent: blocks < BATCH also prep agent row `blk` ----
    if (blk < BATCH) {
        __syncthreads();              // sq reads (e2 reduce) done before reuse
        float rbb = 0.f;
        if (t < DIM) {
            float raw = (t < DS) ? state[blk * DS + t] : action[blk * DA + (t - DS)];
            float bb = raw * rstdl[t];
            agent_bf16[blk * DIM + t] = f2bf(bb);
            rbb = bb * bb;
        }
        if (t < NGROUP) cnt2[(blk * NGROUP + t) * CNT_PAD] = 0;
#pragma unroll
        for (int o = 32; o >= 1; o >>= 1) rbb += __shfl_xor(rbb, o, 64);
        if (lane == 0) sq[wave] = rbb;
        __syncthreads();
        if (t == 0) b2[blk] = sq[0] + sq[1] + sq[2] + sq[3];
    }
}

// ---------------- K2: sampled GEMM -> sd2 fp16 ----------------
__global__ __launch_bounds__(256) void k_sample(const unsigned short* __restrict__ ebf,
                                                const float* __restrict__ e2g,
                                                const unsigned short* __restrict__ agent_bf16,
                                                const float* __restrict__ b2,
                                                _Float16* __restrict__ sd2) {
    __shared__ unsigned short elds[SCHUNK * DIM];   // 8 KB, xor-swizzled chunks
    __shared__ float e2l[SCHUNK];
    __shared__ float b2l[BATCH];

    int t = threadIdx.x, ci = blockIdx.x;
    int lane = t & 63, wave = t >> 6, quad = lane >> 4, lm = lane & 15;
    b2l[t] = b2[t];
    if (t < SCHUNK) e2l[t] = e2g[SAMPLE_STRIDE * (ci * SCHUNK + t)];

    // async staging: wave covers 8 atoms (2 instrs x 1KB)
    {
        const char* gebf = (const char*)ebf;
        char* lbase = (char*)elds + wave * 2048;
#pragma unroll
        for (int q = 0; q < 2; ++q) {
            int aloc = wave * 8 + q * 4 + (lane >> 4);
            int atomg = SAMPLE_STRIDE * (ci * SCHUNK + aloc);
            int ch = (lane & 15) ^ (aloc & 15);
            load_lds16(gebf + (size_t)atomg * 256 + ch * 16, lbase + q * 1024);
        }
    }

    short8v afrag[4][4];
#pragma unroll
    for (int mt = 0; mt < 4; ++mt)
#pragma unroll
        for (int kk = 0; kk < 4; ++kk) {
            int row = wave * 64 + mt * 16 + lm;
            const uint4* p = reinterpret_cast<const uint4*>(agent_bf16 + row * DIM + kk * 32 + quad * 8);
            afrag[mt][kk] = __builtin_bit_cast(short8v, *p);
        }
    __syncthreads();   // drains vmcnt -> LDS staging complete

    f32x4 zero4 = {0.f, 0.f, 0.f, 0.f};
    f32x4 acc[4][2];
#pragma unroll
    for (int mt = 0; mt < 4; ++mt)
#pragma unroll
        for (int nt = 0; nt < 2; ++nt) acc[mt][nt] = zero4;
#pragma unroll
    for (int kk = 0; kk < 4; ++kk) {
        short8v bfrag[2];
#pragma unroll
        for (int nt = 0; nt < 2; ++nt) {
            int a = nt * 16 + lm;
            int ch = (kk * 4 + quad) ^ (a & 15);
            const uint4* p = reinterpret_cast<const uint4*>((const char*)elds + a * 256 + ch * 16);
            bfrag[nt] = __builtin_bit_cast(short8v, *p);
        }
#pragma unroll
        for (int mt = 0; mt < 4; ++mt)
#pragma unroll
            for (int nt = 0; nt < 2; ++nt)
                acc[mt][nt] = __builtin_amdgcn_mfma_f32_16x16x32_bf16(afrag[mt][kk], bfrag[nt], acc[mt][nt], 0, 0, 0);
    }

#pragma unroll
    for (int mt = 0; mt < 4; ++mt)
#pragma unroll
        for (int nt = 0; nt < 2; ++nt) {
            int atoml = nt * 16 + lm;
            float e2v = e2l[atoml];
#pragma unroll
            for (int r = 0; r < 4; ++r) {
                int row = wave * 64 + mt * 16 + quad * 4 + r;
                float d2 = b2l[row] + fmaf(-2.0f, acc[mt][nt][r], e2v);
                sd2[(size_t)row * SAMPLE_N + ci * SCHUNK + atoml] = (_Float16)d2;
            }
        }
}

// ---------------- K3: per-row tau from sample ----------------
__global__ __launch_bounds__(256) void k_tau(const _Float16* __restrict__ sd2,
                                             const float* __restrict__ b2,
                                             float* __restrict__ thr) {
    __shared__ unsigned int hist[TAU_BINS];
    __shared__ unsigned int part[256];
    int t = threadIdx.x, row = blockIdx.x;
    for (int i = t; i < TAU_BINS; i += 256) hist[i] = 0;
    __syncthreads();
    const uint4* r4 = reinterpret_cast<const uint4*>(sd2 + (size_t)row * SAMPLE_N);  // 2048 uint4
#pragma unroll
    for (int it = 0; it < 8; ++it) {
        uint4 v = r4[t + 256 * it];
        unsigned int wv[4] = {v.x, v.y, v.z, v.w};
#pragma unroll
        for (int q = 0; q < 4; ++q)
#pragma unroll
            for (int hh = 0; hh < 2; ++hh) {
                unsigned short bits = (unsigned short)((wv[q] >> (16 * hh)) & 0xffffu);
                float d2f = (float)__builtin_bit_cast(_Float16, bits);
                int bn = (int)(sqrtf(fmaxf(d2f, 0.f)) * TAU_SCALE);
                bn = bn < 0 ? 0 : (bn > TAU_BINS - 1 ? TAU_BINS - 1 : bn);
                atomicAdd(&hist[bn], 1u);
            }
    }
    __syncthreads();
    unsigned int s = 0;
#pragma unroll
    for (int i = 0; i < 8; ++i) s += hist[t * 8 + i];
    part[t] = s;
    __syncthreads();
    if (t == 0) {
        unsigned int cum = 0;
        int B = TAU_BINS - 1;
        for (int c = 0; c < 256; ++c) {
            if (cum + part[c] >= SAMPLE_TARGET) {
                unsigned int cc = cum;
                for (int i = 0; i < 8; ++i) {
                    cc += hist[c * 8 + i];
                    if (cc >= SAMPLE_TARGET) { B = c * 8 + i; break; }
                }
                break;
            }
            cum += part[c];
        }
        int tb = B + MARGIN_BINS;
        if (tb > TAU_BINS - 1) tb = TAU_BINS - 1;
        float td = (float)(tb + 1) * (1.0f / TAU_SCALE);
        thr[row] = td * td - b2[row];   // compare:  e2 - 2*dot <= thr
    }
}

// ---------------- K4: full GEMM + WAVE-PRIVATE candidate compaction ----------------
// Round-8 (= round-7 resubmit; r7 was an infra failure, no data): round-2
// geometry (NCHUNK=64, 3125 blocks, single chunk, acc[4][4]). Key fact: each
// wave's accumulator tile covers rows [wave*64, wave*64+64) EXACTLY -> rows are
// wave-private -> the whole compaction (stage, per-row count, global RMW,
// scatter) runs per-wave with NO cross-wave barriers. Lane l owns row
// wave*64+l. Wave-internal LDS visibility = lockstep execution + the compiler's
// conservative lgkmcnt waits (all stage/rowcnt writes are issued in program
// order by the same wave that later reads them). The cross-XCD RMW latency
// (~1-2Kcyc, previously exposed to all 4 waves via two barriers, 3125x) now
// stalls only its own wave; other resident waves keep issuing (m114).
// Barriers: 3 -> 1 (only the staging drain remains).
__global__ __launch_bounds__(256, 4) void k_compact(const unsigned short* __restrict__ ebf,
                                                    const float* __restrict__ e2g,
                                                    const unsigned short* __restrict__ agent_bf16,
                                                    const float* __restrict__ thr,
                                                    const float* __restrict__ b2,
                                                    int* __restrict__ cnt2,
                                                    float* __restrict__ cand2) {
    __shared__ unsigned short elds[NCHUNK * DIM];   // 16 KB, xor-swizzled chunks
    __shared__ float e2l[NCHUNK];
    __shared__ float thrl[BATCH], b2l[BATCH];
    __shared__ unsigned int stage_rl[4][STAGE_W];   // wave-private: local row id
    __shared__ float stage_d2[4][STAGE_W];
    __shared__ int rowcnt[4][64], rowbase[4][64], rowoff[4][64];
    __shared__ int nlds[4][16];                     // 1 counter / wave, 64B apart

    int t = threadIdx.x, chunkblk = blockIdx.x;
    int grp = chunkblk % NGROUP;                    // spread concurrent blocks
    int lane = t & 63, wave = t >> 6, quad = lane >> 4, lm = lane & 15;
    thrl[t] = thr[t];
    b2l[t] = b2[t];
    if (t < NCHUNK) e2l[t] = e2g[chunkblk * NCHUNK + t];
    rowcnt[wave][lane] = 0;
    rowoff[wave][lane] = 0;
    if (lane == 0) nlds[wave][0] = 0;

    // async staging: wave covers 16 atoms (4 instrs x 1KB)
    {
        const char* gbase = (const char*)ebf + (size_t)chunkblk * NCHUNK * 256;
        char* lbase = (char*)elds + wave * 4096;
#pragma unroll
        for (int q = 0; q < 4; ++q) {
            int aloc = wave * 16 + q * 4 + (lane >> 4);
            int ch = (lane & 15) ^ (aloc & 15);
            load_lds16(gbase + (size_t)aloc * 256 + ch * 16, lbase + q * 1024);
        }
    }
    __syncthreads();   // drains vmcnt -> staging + LDS scalars ready (ONLY barrier)

    f32x4 zero4 = {0.f, 0.f, 0.f, 0.f};
    f32x4 acc[4][4];
#pragma unroll
    for (int mt = 0; mt < 4; ++mt)
#pragma unroll
        for (int nt = 0; nt < 4; ++nt) acc[mt][nt] = zero4;

#pragma unroll
    for (int kk = 0; kk < 4; ++kk) {
        short8v afrag[4];
#pragma unroll
        for (int mt = 0; mt < 4; ++mt) {
            int row = wave * 64 + mt * 16 + lm;
            const uint4* p = reinterpret_cast<const uint4*>(agent_bf16 + row * DIM + kk * 32 + quad * 8);
            afrag[mt] = __builtin_bit_cast(short8v, *p);
        }
#pragma unroll
        for (int nt = 0; nt < 4; ++nt) {
            int a = nt * 16 + lm;
            int ch = (kk * 4 + quad) ^ (a & 15);
            const uint4* p = reinterpret_cast<const uint4*>((const char*)elds + a * 256 + ch * 16);
            short8v bfrag = __builtin_bit_cast(short8v, *p);
#pragma unroll
            for (int mt = 0; mt < 4; ++mt)
                acc[mt][nt] = __builtin_amdgcn_mfma_f32_16x16x32_bf16(afrag[mt], bfrag, acc[mt][nt], 0, 0, 0);
        }
    }

    // wave-private push: (rowlocal, d2) into this wave's stage
#pragma unroll
    for (int mt = 0; mt < 4; ++mt)
#pragma unroll
        for (int nt = 0; nt < 4; ++nt) {
            int atoml = nt * 16 + lm;
            float e2v = e2l[atoml];
#pragma unroll
            for (int r = 0; r < 4; ++r) {
                int rl = mt * 16 + quad * 4 + r;        // 0..63, wave-local row
                int row = wave * 64 + rl;
                float lhs = fmaf(-2.0f, acc[mt][nt][r], e2v);
                if (lhs <= thrl[row]) {
                    int p = atomicAdd(&nlds[wave][0], 1);
                    if (p < STAGE_W) {
                        stage_rl[wave][p] = (unsigned int)rl;
                        stage_d2[wave][p] = b2l[row] + lhs;
                        atomicAdd(&rowcnt[wave][rl], 1);
                    }
                }
            }
        }

    // wave-private epilogue (no cross-wave barrier):
    // lockstep + compiler lgkmcnt waits guarantee this wave's pushes retired
    // before these reads.
    int n = nlds[wave][0];
    n = n < STAGE_W ? n : STAGE_W;

    int rc = rowcnt[wave][lane];                    // lane l owns row wave*64+l
    if (rc > 0)
        rowbase[wave][lane] =
            atomicAdd(&cnt2[((wave * 64 + lane) * NGROUP + grp) * CNT_PAD], rc);

    for (int i = lane; i < n; i += 64) {
        int rl = (int)stage_rl[wave][i];
        int pos = rowbase[wave][rl] + atomicAdd(&rowoff[wave][rl], 1);
        if (pos < GSLOTS)
            cand2[((wave * 64 + rl) * NGROUP + grp) * GSLOTS + pos] = stage_d2[wave][i];
    }
}

// ---------------- K5: selection-based greedy cost (uniform weights; no sort) ----------------
__global__ __launch_bounds__(256) void k_cost(const float* __restrict__ cand2,
                                              const int* __restrict__ cnt2,
                                              const float* __restrict__ weights,
                                              const float* __restrict__ thr,
                                              const float* __restrict__ b2,
                                              float* __restrict__ out) {
    __shared__ float cdl[CAND_MAX];
    __shared__ unsigned int hist[HBINS];
    __shared__ unsigned int part[256];
    __shared__ int gcnt[NGROUP], goff[NGROUP + 1];
    __shared__ float bb[64];
    __shared__ float wred[4];
    __shared__ unsigned int wtot[4];
    __shared__ int nb;
    __shared__ int Bs, c0s;
    __shared__ float dmin2S;

    int t = threadIdx.x, row = blockIdx.x;
    int lane = t & 63, wave = t >> 6;
    for (int i = t; i < HBINS; i += 256) hist[i] = 0;
    if (t < NGROUP) {
        int nn = cnt2[(row * NGROUP + t) * CNT_PAD];
        gcnt[t] = nn < GSLOTS ? nn : GSLOTS;
    }
    if (t == 0) nb = 0;
    __syncthreads();
    if (t == 0) {
        int s = 0;
        for (int g = 0; g < NGROUP; ++g) { goff[g] = s; s += gcnt[g]; }
        goff[NGROUP] = s < CAND_MAX ? s : CAND_MAX;
    }
    __syncthreads();
    int nc = goff[NGROUP];
    float tau2 = thr[row] + b2[row];           // all candidates have d2 <= tau2

    // copy candidate d2 values into LDS (wave per group, round-robin)
    {
        for (int g = wave; g < NGROUP; g += 4) {
            int n = gcnt[g], base = goff[g];
            const float* src = cand2 + (row * NGROUP + g) * GSLOTS;
            for (int i = lane; i < n; i += 64) {
                int slot = base + i;
                if (slot < CAND_MAX) cdl[slot] = src[i];
            }
        }
    }
    __syncthreads();

    // block min of d2 (shuffle + tiny LDS)
    float mn = tau2;
    for (int i = t; i < nc; i += 256) mn = fminf(mn, cdl[i]);
#pragma unroll
    for (int o = 32; o >= 1; o >>= 1) mn = fminf(mn, __shfl_xor(mn, o, 64));
    if (lane == 0) wred[wave] = mn;
    __syncthreads();
    if (t == 0) dmin2S = fminf(fminf(wred[0], wred[1]), fminf(wred[2], wred[3]));
    __syncthreads();
    float dmin2 = dmin2S;
    float denom = tau2 - dmin2;
    float binscale = (float)HBINS / fmaxf(denom, 1e-12f);

    // count histogram over [dmin2, tau2] (native int LDS atomics, spread bins)
    for (int i = t; i < nc; i += 256) {
        int bn = (int)((cdl[i] - dmin2) * binscale);
        bn = bn < 0 ? 0 : (bn > HBINS - 1 ? HBINS - 1 : bn);
        atomicAdd(&hist[bn], 1u);
    }
    __syncthreads();

    // two-level parallel prefix: part[t] = hist[2t]+hist[2t+1]; shuffle scan per wave
    unsigned int pv = hist[2 * t] + hist[2 * t + 1];
    part[t] = pv;
    unsigned int inc = pv;
#pragma unroll
    for (int o = 1; o < 64; o <<= 1) {
        unsigned int up = __shfl_up(inc, o, 64);
        if (lane >= o) inc += up;
    }
    if (lane == 63) wtot[wave] = inc;
    __syncthreads();
    unsigned int woffs = 0;
    for (int w = 0; w < wave; ++w) woffs += wtot[w];
    unsigned int incl = inc + woffs;           // inclusive cum over pairs
    unsigned int before = incl - pv;           // cum before this pair
    // locate rank-200 bin (unique thread)
    if (before < 200u && incl >= 200u) {
        unsigned int h0 = hist[2 * t];
        if (before + h0 >= 200u) { Bs = 2 * t; c0s = (int)before; }
        else { Bs = 2 * t + 1; c0s = (int)(before + h0); }
    }
    __syncthreads();
    int B = Bs, c0 = c0s;

    // per-thread: sum d for bins < B; compact boundary bin (int atomic, tiny count)
    float sloc = 0.f;
    for (int i = t; i < nc; i += 256) {
        float d2 = cdl[i];
        int bn = (int)((d2 - dmin2) * binscale);
        bn = bn < 0 ? 0 : (bn > HBINS - 1 ? HBINS - 1 : bn);
        if (bn < B) sloc += sqrtf(fmaxf(d2, 1e-12f));
        else if (bn == B) {
            int p = atomicAdd(&nb, 1);
            if (p < 64) bb[p] = sqrtf(fmaxf(d2, 1e-12f));
        }
    }
#pragma unroll
    for (int o = 32; o >= 1; o >>= 1) sloc += __shfl_xor(sloc, o, 64);
    if (lane == 0) wred[wave] = sloc;
    __syncthreads();

    if (t == 0) {
        float s0 = wred[0] + wred[1] + wred[2] + wred[3];
        int m = nb < 64 ? nb : 64;
        // insertion sort ascending (m is tiny)
        for (int i = 1; i < m; ++i) {
            float v = bb[i]; int j = i - 1;
            while (j >= 0 && bb[j] > v) { bb[j + 1] = bb[j]; --j; }
            bb[j + 1] = v;
        }
        int need = 200 - c0;            // >= 1 by construction
        if (need > m) need = m;         // paranoia guard
        float s199 = s0;                // ranks 0..c0-1
        for (int i = 0; i < need - 1; ++i) s199 += bb[i];   // ranks c0..198
        float d200 = bb[need - 1];      // rank 199
        float w0 = weights[0];
        float cumw = 0.f;               // replicate reference's sequential fp32 cumsum
        for (int i = 0; i < 199; ++i) cumw += w0;
        float TGT = target_w();
        float cost = w0 * s199 + (TGT - cumw) * d200;
        out[row] = 5.0f * expf(-(float)RBW * cost);
    }
}

// ---------------- launch ----------------
extern "C" void kernel_launch(void* const* d_in, const int* in_sizes, int n_in,
                              void* d_out, int out_size, void* d_ws, size_t ws_size,
                              hipStream_t stream) {
    const float* state   = (const float*)d_in[0];
    const float* action  = (const float*)d_in[1];
    const float* experts = (const float*)d_in[2];
    const float* weights = (const float*)d_in[3];
    const float* stdv    = (const float*)d_in[5];
    float* out = (float*)d_out;

    if (ws_size < (size_t)WS_NEEDED) return;

    char* ws = (char*)d_ws;
    unsigned short* ebf        = (unsigned short*)(ws + OFF_EBF);
    float* e2g                 = (float*)(ws + OFF_E2);
    _Float16* sd2              = (_Float16*)(ws + OFF_SD2);
    unsigned short* agent_bf16 = (unsigned short*)(ws + OFF_ABF);
    float* b2                  = (float*)(ws + OFF_B2);
    float* thr                 = (float*)(ws + OFF_THR);
    int* cnt2                  = (int*)(ws + OFF_CNT2);
    float* cand2               = (float*)(ws + OFF_CAND2);

    k_prep<<<PREP_BLK, 256, 0, stream>>>(experts, stdv, state, action, ebf, e2g, agent_bf16, b2, cnt2);
    k_sample<<<SBLK, 256, 0, stream>>>(ebf, e2g, agent_bf16, b2, sd2);
    k_tau<<<BATCH, 256, 0, stream>>>(sd2, b2, thr);
    k_compact<<<NBLK, 256, 0, stream>>>(ebf, e2g, agent_bf16, thr, b2, cnt2, cand2);
    k_cost<<<BATCH, 256, 0, stream>>>(cand2, cnt2, weights, thr, b2, out);
}

// Round 9
// 222.128 us; speedup vs baseline: 1.2925x; 1.0806x over previous
//
#include <hip/hip_runtime.h>
#include <hip/hip_bf16.h>
#include <hip/hip_fp16.h>

// ---------------- problem constants ----------------
#define BATCH 256
#define NEXP 200000
#define DS 96
#define DA 32
#define DIM 128
#define NCHUNK 64                     // atoms per k_compact block
#define NBLK (NEXP / NCHUNK)          // 3125
#define SAMPLE_N 16384
#define SAMPLE_STRIDE 12              // 12*16383 = 196596 < 200000
#define SCHUNK 32                     // atoms per k_sample block
#define SBLK (SAMPLE_N / SCHUNK)      // 512
#define SAMPLE_TARGET 64              // ~64/16384 quantile -> ~780 full candidates
#define MARGIN_BINS 4                 // +0.25 in d safety margin
#define TAU_BINS 2048
#define TAU_SCALE 16.0f               // bin = floor(d * 16), covers d < 128
#define CAND_MAX 2048
#define STAGE_W 256                   // per-wave stage slots (expect ~25/wave)
#define CNT_PAD 16                    // one counter per 64B cache line
#define NGROUP 32                     // block groups (contention spreading)
#define GSLOTS 128                    // slots per (row,group); expected ~25
#define HBINS 512                     // k_cost selection histogram bins
#define RBW 441.94173824159216        // 5.0*1000/sqrt(128)

static __device__ __forceinline__ float target_w() { return (float)(1.0 / 1000.0 - 1e-6); }

typedef short short8v __attribute__((ext_vector_type(8)));
typedef float f32x4 __attribute__((ext_vector_type(4)));

// ws layout (bytes) -- ebf/e2g slots retained but unused after round-9 fusion
#define OFF_EBF   0                   // (unused)
#define OFF_E2    51200000            // (unused)
#define OFF_SD2   52000000            // fp16 [BATCH][SAMPLE_N]       =  8,388,608
#define OFF_ABF   60388608            // ushort [BATCH*DIM]           =     65,536
#define OFF_B2    60454144            // float  [BATCH]               =      1,024
#define OFF_THR   60455168            // float  [BATCH]               =      1,024
#define OFF_CNT2  60456192            // int [BATCH*NGROUP*CNT_PAD]   =    524,288
#define OFF_CAND2 60980480            // float [BATCH*NGROUP*GSLOTS]  =  4,194,304
#define WS_NEEDED 65174784

__device__ __forceinline__ unsigned short f2bf(float x) {
    __hip_bfloat16 h = __float2bfloat16(x);
    return __builtin_bit_cast(unsigned short, h);
}

__device__ __forceinline__ unsigned int pk2bf(float a, float b) {
    return (unsigned int)f2bf(a) | ((unsigned int)f2bf(b) << 16);
}

// ---------------- K0: agent prep (+ zero group counters) ----------------
__global__ __launch_bounds__(128) void k_agent(const float* __restrict__ state,
                                               const float* __restrict__ action,
                                               const float* __restrict__ stdv,
                                               unsigned short* __restrict__ agent_bf16,
                                               float* __restrict__ b2,
                                               int* __restrict__ cnt2) {
    int b = blockIdx.x, d = threadIdx.x;
    float raw = (d < DS) ? state[b * DS + d] : action[b * DA + (d - DS)];
    float bb = raw / stdv[d];
    agent_bf16[b * DIM + d] = f2bf(bb);
    if (d < NGROUP) cnt2[(b * NGROUP + d) * CNT_PAD] = 0;
    __shared__ float red[128];
    red[d] = bb * bb;
    __syncthreads();
    for (int s = 64; s > 0; s >>= 1) {
        if (d < s) red[d] += red[d + s];
        __syncthreads();
    }
    if (d == 0) b2[b] = red[0];
}

// ---------------- K2: sampled GEMM from RAW f32 experts -> sd2 fp16 ----------------
// Round-9: no ebf/e2g precompute. Reg-staged: 8 threads/atom load 64B f32
// contiguous, normalize by rstd, compute e2 partials (8-lane shfl reduce),
// pack bf16 and ds_write into the SAME xor-swizzled layout the B-frag reads
// expect (slot c^(a&15) holds chunk c). bf16 rounding identical to the old
// k_prep path (__float2bfloat16).
__global__ __launch_bounds__(256) void k_sample(const float* __restrict__ experts,
                                                const float* __restrict__ stdv,
                                                const unsigned short* __restrict__ agent_bf16,
                                                const float* __restrict__ b2,
                                                _Float16* __restrict__ sd2) {
    __shared__ __align__(16) unsigned short elds[SCHUNK * DIM];   // 8 KB swizzled bf16
    __shared__ float e2l[SCHUNK];
    __shared__ float b2l[BATCH];
    __shared__ float rstdl[DIM];

    int t = threadIdx.x, ci = blockIdx.x;
    int lane = t & 63, wave = t >> 6, quad = lane >> 4, lm = lane & 15;
    b2l[t] = b2[t];
    if (t < DIM) rstdl[t] = 1.0f / stdv[t];
    __syncthreads();                     // rstdl visible

    // reg-stage: atom al = t>>3, slice p = t&7 (16 dims = 4 float4 = 2 chunks)
    {
        int al = t >> 3, p = t & 7;
        int ag = SAMPLE_STRIDE * (ci * SCHUNK + al);
        const float4* g4 = reinterpret_cast<const float4*>(experts + (size_t)ag * DIM + p * 16);
        float4 v0 = g4[0], v1 = g4[1], v2 = g4[2], v3 = g4[3];
        int db = p * 16;
        float n0 = v0.x * rstdl[db + 0],  n1 = v0.y * rstdl[db + 1];
        float n2 = v0.z * rstdl[db + 2],  n3 = v0.w * rstdl[db + 3];
        float n4 = v1.x * rstdl[db + 4],  n5 = v1.y * rstdl[db + 5];
        float n6 = v1.z * rstdl[db + 6],  n7 = v1.w * rstdl[db + 7];
        float n8 = v2.x * rstdl[db + 8],  n9 = v2.y * rstdl[db + 9];
        float na = v2.z * rstdl[db + 10], nb = v2.w * rstdl[db + 11];
        float nc = v3.x * rstdl[db + 12], nd = v3.y * rstdl[db + 13];
        float ne = v3.z * rstdl[db + 14], nf = v3.w * rstdl[db + 15];
        float e2p = n0*n0 + n1*n1 + n2*n2 + n3*n3 + n4*n4 + n5*n5 + n6*n6 + n7*n7
                  + n8*n8 + n9*n9 + na*na + nb*nb + nc*nc + nd*nd + ne*ne + nf*nf;
        uint4 w0 = { pk2bf(n0, n1), pk2bf(n2, n3), pk2bf(n4, n5), pk2bf(n6, n7) };
        uint4 w1 = { pk2bf(n8, n9), pk2bf(na, nb), pk2bf(nc, nd), pk2bf(ne, nf) };
        int sw = al & 15;
        uint4* lp = reinterpret_cast<uint4*>(elds);
        lp[al * 16 + ((2 * p)     ^ sw)] = w0;
        lp[al * 16 + ((2 * p + 1) ^ sw)] = w1;
        e2p += __shfl_xor(e2p, 1, 64);
        e2p += __shfl_xor(e2p, 2, 64);
        e2p += __shfl_xor(e2p, 4, 64);
        if (p == 0) e2l[al] = e2p;
    }

    short8v afrag[4][4];
#pragma unroll
    for (int mt = 0; mt < 4; ++mt)
#pragma unroll
        for (int kk = 0; kk < 4; ++kk) {
            int row = wave * 64 + mt * 16 + lm;
            const uint4* p = reinterpret_cast<const uint4*>(agent_bf16 + row * DIM + kk * 32 + quad * 8);
            afrag[mt][kk] = __builtin_bit_cast(short8v, *p);
        }
    __syncthreads();   // staging + e2l complete

    f32x4 zero4 = {0.f, 0.f, 0.f, 0.f};
    f32x4 acc[4][2];
#pragma unroll
    for (int mt = 0; mt < 4; ++mt)
#pragma unroll
        for (int nt = 0; nt < 2; ++nt) acc[mt][nt] = zero4;
#pragma unroll
    for (int kk = 0; kk < 4; ++kk) {
        short8v bfrag[2];
#pragma unroll
        for (int nt = 0; nt < 2; ++nt) {
            int a = nt * 16 + lm;
            int ch = (kk * 4 + quad) ^ (a & 15);
            const uint4* p = reinterpret_cast<const uint4*>((const char*)elds + a * 256 + ch * 16);
            bfrag[nt] = __builtin_bit_cast(short8v, *p);
        }
#pragma unroll
        for (int mt = 0; mt < 4; ++mt)
#pragma unroll
            for (int nt = 0; nt < 2; ++nt)
                acc[mt][nt] = __builtin_amdgcn_mfma_f32_16x16x32_bf16(afrag[mt][kk], bfrag[nt], acc[mt][nt], 0, 0, 0);
    }

#pragma unroll
    for (int mt = 0; mt < 4; ++mt)
#pragma unroll
        for (int nt = 0; nt < 2; ++nt) {
            int atoml = nt * 16 + lm;
            float e2v = e2l[atoml];
#pragma unroll
            for (int r = 0; r < 4; ++r) {
                int row = wave * 64 + mt * 16 + quad * 4 + r;
                float d2 = b2l[row] + fmaf(-2.0f, acc[mt][nt][r], e2v);
                sd2[(size_t)row * SAMPLE_N + ci * SCHUNK + atoml] = (_Float16)d2;
            }
        }
}

// ---------------- K3: per-row tau from sample ----------------
__global__ __launch_bounds__(256) void k_tau(const _Float16* __restrict__ sd2,
                                             const float* __restrict__ b2,
                                             float* __restrict__ thr) {
    __shared__ unsigned int hist[TAU_BINS];
    __shared__ unsigned int part[256];
    int t = threadIdx.x, row = blockIdx.x;
    for (int i = t; i < TAU_BINS; i += 256) hist[i] = 0;
    __syncthreads();
    const uint4* r4 = reinterpret_cast<const uint4*>(sd2 + (size_t)row * SAMPLE_N);  // 2048 uint4
#pragma unroll
    for (int it = 0; it < 8; ++it) {
        uint4 v = r4[t + 256 * it];
        unsigned int wv[4] = {v.x, v.y, v.z, v.w};
#pragma unroll
        for (int q = 0; q < 4; ++q)
#pragma unroll
            for (int hh = 0; hh < 2; ++hh) {
                unsigned short bits = (unsigned short)((wv[q] >> (16 * hh)) & 0xffffu);
                float d2f = (float)__builtin_bit_cast(_Float16, bits);
                int bn = (int)(sqrtf(fmaxf(d2f, 0.f)) * TAU_SCALE);
                bn = bn < 0 ? 0 : (bn > TAU_BINS - 1 ? TAU_BINS - 1 : bn);
                atomicAdd(&hist[bn], 1u);
            }
    }
    __syncthreads();
    unsigned int s = 0;
#pragma unroll
    for (int i = 0; i < 8; ++i) s += hist[t * 8 + i];
    part[t] = s;
    __syncthreads();
    if (t == 0) {
        unsigned int cum = 0;
        int B = TAU_BINS - 1;
        for (int c = 0; c < 256; ++c) {
            if (cum + part[c] >= SAMPLE_TARGET) {
                unsigned int cc = cum;
                for (int i = 0; i < 8; ++i) {
                    cc += hist[c * 8 + i];
                    if (cc >= SAMPLE_TARGET) { B = c * 8 + i; break; }
                }
                break;
            }
            cum += part[c];
        }
        int tb = B + MARGIN_BINS;
        if (tb > TAU_BINS - 1) tb = TAU_BINS - 1;
        float td = (float)(tb + 1) * (1.0f / TAU_SCALE);
        thr[row] = td * td - b2[row];   // compare:  e2 - 2*dot <= thr
    }
}

// ---------------- K4: fused normalize + GEMM + wave-private compaction ----------------
// Round-9: k_prep deleted. k_compact reads RAW f32 experts (each atom touched
// exactly once across the grid), normalizes in-register, computes e2 via 4-lane
// shfl reduce, packs bf16, and ds_writes into the same xor-swizzled layout.
// Removes the 154MB k_prep stream (102.4R + 51.2W + e2) at the cost of k_compact
// staging 2x bytes (f32 vs bf16) -- it is latency-bound at 425 GB/s effective,
// so the extra bytes ride free. Wave-private epilogue (round-8 win) untouched.
__global__ __launch_bounds__(256, 4) void k_compact(const float* __restrict__ experts,
                                                    const float* __restrict__ stdv,
                                                    const unsigned short* __restrict__ agent_bf16,
                                                    const float* __restrict__ thr,
                                                    const float* __restrict__ b2,
                                                    int* __restrict__ cnt2,
                                                    float* __restrict__ cand2) {
    __shared__ __align__(16) unsigned short elds[NCHUNK * DIM];   // 16 KB swizzled bf16
    __shared__ float e2l[NCHUNK];
    __shared__ float thrl[BATCH], b2l[BATCH];
    __shared__ float rstdl[DIM];
    __shared__ unsigned int stage_rl[4][STAGE_W];   // wave-private: local row id
    __shared__ float stage_d2[4][STAGE_W];
    __shared__ int rowcnt[4][64], rowbase[4][64], rowoff[4][64];
    __shared__ int nlds[4][16];                     // 1 counter / wave, 64B apart

    int t = threadIdx.x, chunkblk = blockIdx.x;
    int grp = chunkblk % NGROUP;                    // spread concurrent blocks
    int lane = t & 63, wave = t >> 6, quad = lane >> 4, lm = lane & 15;
    thrl[t] = thr[t];
    b2l[t] = b2[t];
    if (t < DIM) rstdl[t] = 1.0f / stdv[t];
    rowcnt[wave][lane] = 0;
    rowoff[wave][lane] = 0;
    if (lane == 0) nlds[wave][0] = 0;
    __syncthreads();                     // rstdl visible

    // reg-stage: atom al = t>>2, slice p = t&3 (32 dims = 8 float4 = 4 chunks)
    {
        int al = t >> 2, p = t & 3;
        const float4* g4 = reinterpret_cast<const float4*>(
            experts + ((size_t)(chunkblk * NCHUNK + al)) * DIM + p * 32);
        float e2p = 0.f;
        int sw = al & 15;
        uint4* lp = reinterpret_cast<uint4*>(elds);
#pragma unroll
        for (int k = 0; k < 4; ++k) {              // chunk k: dims p*32+k*8 .. +8
            float4 a = g4[2 * k], b = g4[2 * k + 1];
            int db = p * 32 + k * 8;
            float m0 = a.x * rstdl[db + 0], m1 = a.y * rstdl[db + 1];
            float m2 = a.z * rstdl[db + 2], m3 = a.w * rstdl[db + 3];
            float m4 = b.x * rstdl[db + 4], m5 = b.y * rstdl[db + 5];
            float m6 = b.z * rstdl[db + 6], m7 = b.w * rstdl[db + 7];
            e2p += m0*m0 + m1*m1 + m2*m2 + m3*m3 + m4*m4 + m5*m5 + m6*m6 + m7*m7;
            uint4 w = { pk2bf(m0, m1), pk2bf(m2, m3), pk2bf(m4, m5), pk2bf(m6, m7) };
            lp[al * 16 + ((p * 4 + k) ^ sw)] = w;
        }
        e2p += __shfl_xor(e2p, 1, 64);
        e2p += __shfl_xor(e2p, 2, 64);
        if (p == 0) e2l[al] = e2p;
    }
    __syncthreads();   // staging + e2l + thrl/b2l ready (2nd and last barrier)

    f32x4 zero4 = {0.f, 0.f, 0.f, 0.f};
    f32x4 acc[4][4];
#pragma unroll
    for (int mt = 0; mt < 4; ++mt)
#pragma unroll
        for (int nt = 0; nt < 4; ++nt) acc[mt][nt] = zero4;

#pragma unroll
    for (int kk = 0; kk < 4; ++kk) {
        short8v afrag[4];
#pragma unroll
        for (int mt = 0; mt < 4; ++mt) {
            int row = wave * 64 + mt * 16 + lm;
            const uint4* p = reinterpret_cast<const uint4*>(agent_bf16 + row * DIM + kk * 32 + quad * 8);
            afrag[mt] = __builtin_bit_cast(short8v, *p);
        }
#pragma unroll
        for (int nt = 0; nt < 4; ++nt) {
            int a = nt * 16 + lm;
            int ch = (kk * 4 + quad) ^ (a & 15);
            const uint4* p = reinterpret_cast<const uint4*>((const char*)elds + a * 256 + ch * 16);
            short8v bfrag = __builtin_bit_cast(short8v, *p);
#pragma unroll
            for (int mt = 0; mt < 4; ++mt)
                acc[mt][nt] = __builtin_amdgcn_mfma_f32_16x16x32_bf16(afrag[mt], bfrag, acc[mt][nt], 0, 0, 0);
        }
    }

    // wave-private push: (rowlocal, d2) into this wave's stage
#pragma unroll
    for (int mt = 0; mt < 4; ++mt)
#pragma unroll
        for (int nt = 0; nt < 4; ++nt) {
            int atoml = nt * 16 + lm;
            float e2v = e2l[atoml];
#pragma unroll
            for (int r = 0; r < 4; ++r) {
                int rl = mt * 16 + quad * 4 + r;        // 0..63, wave-local row
                int row = wave * 64 + rl;
                float lhs = fmaf(-2.0f, acc[mt][nt][r], e2v);
                if (lhs <= thrl[row]) {
                    int p = atomicAdd(&nlds[wave][0], 1);
                    if (p < STAGE_W) {
                        stage_rl[wave][p] = (unsigned int)rl;
                        stage_d2[wave][p] = b2l[row] + lhs;
                        atomicAdd(&rowcnt[wave][rl], 1);
                    }
                }
            }
        }

    // wave-private epilogue (no cross-wave barrier): lockstep + compiler
    // lgkmcnt waits guarantee this wave's pushes retired before these reads.
    int n = nlds[wave][0];
    n = n < STAGE_W ? n : STAGE_W;

    int rc = rowcnt[wave][lane];                    // lane l owns row wave*64+l
    if (rc > 0)
        rowbase[wave][lane] =
            atomicAdd(&cnt2[((wave * 64 + lane) * NGROUP + grp) * CNT_PAD], rc);

    for (int i = lane; i < n; i += 64) {
        int rl = (int)stage_rl[wave][i];
        int pos = rowbase[wave][rl] + atomicAdd(&rowoff[wave][rl], 1);
        if (pos < GSLOTS)
            cand2[((wave * 64 + rl) * NGROUP + grp) * GSLOTS + pos] = stage_d2[wave][i];
    }
}

// ---------------- K5: selection-based greedy cost (uniform weights; no sort) ----------------
__global__ __launch_bounds__(256) void k_cost(const float* __restrict__ cand2,
                                              const int* __restrict__ cnt2,
                                              const float* __restrict__ weights,
                                              const float* __restrict__ thr,
                                              const float* __restrict__ b2,
                                              float* __restrict__ out) {
    __shared__ float cdl[CAND_MAX];
    __shared__ unsigned int hist[HBINS];
    __shared__ unsigned int part[256];
    __shared__ int gcnt[NGROUP], goff[NGROUP + 1];
    __shared__ float bb[64];
    __shared__ float wred[4];
    __shared__ unsigned int wtot[4];
    __shared__ int nb;
    __shared__ int Bs, c0s;
    __shared__ float dmin2S;

    int t = threadIdx.x, row = blockIdx.x;
    int lane = t & 63, wave = t >> 6;
    for (int i = t; i < HBINS; i += 256) hist[i] = 0;
    if (t < NGROUP) {
        int nn = cnt2[(row * NGROUP + t) * CNT_PAD];
        gcnt[t] = nn < GSLOTS ? nn : GSLOTS;
    }
    if (t == 0) nb = 0;
    __syncthreads();
    if (t == 0) {
        int s = 0;
        for (int g = 0; g < NGROUP; ++g) { goff[g] = s; s += gcnt[g]; }
        goff[NGROUP] = s < CAND_MAX ? s : CAND_MAX;
    }
    __syncthreads();
    int nc = goff[NGROUP];
    float tau2 = thr[row] + b2[row];           // all candidates have d2 <= tau2

    // copy candidate d2 values into LDS (wave per group, round-robin)
    {
        for (int g = wave; g < NGROUP; g += 4) {
            int n = gcnt[g], base = goff[g];
            const float* src = cand2 + (row * NGROUP + g) * GSLOTS;
            for (int i = lane; i < n; i += 64) {
                int slot = base + i;
                if (slot < CAND_MAX) cdl[slot] = src[i];
            }
        }
    }
    __syncthreads();

    // block min of d2 (shuffle + tiny LDS)
    float mn = tau2;
    for (int i = t; i < nc; i += 256) mn = fminf(mn, cdl[i]);
#pragma unroll
    for (int o = 32; o >= 1; o >>= 1) mn = fminf(mn, __shfl_xor(mn, o, 64));
    if (lane == 0) wred[wave] = mn;
    __syncthreads();
    if (t == 0) dmin2S = fminf(fminf(wred[0], wred[1]), fminf(wred[2], wred[3]));
    __syncthreads();
    float dmin2 = dmin2S;
    float denom = tau2 - dmin2;
    float binscale = (float)HBINS / fmaxf(denom, 1e-12f);

    // count histogram over [dmin2, tau2] (native int LDS atomics, spread bins)
    for (int i = t; i < nc; i += 256) {
        int bn = (int)((cdl[i] - dmin2) * binscale);
        bn = bn < 0 ? 0 : (bn > HBINS - 1 ? HBINS - 1 : bn);
        atomicAdd(&hist[bn], 1u);
    }
    __syncthreads();

    // two-level parallel prefix: part[t] = hist[2t]+hist[2t+1]; shuffle scan per wave
    unsigned int pv = hist[2 * t] + hist[2 * t + 1];
    part[t] = pv;
    unsigned int inc = pv;
#pragma unroll
    for (int o = 1; o < 64; o <<= 1) {
        unsigned int up = __shfl_up(inc, o, 64);
        if (lane >= o) inc += up;
    }
    if (lane == 63) wtot[wave] = inc;
    __syncthreads();
    unsigned int woffs = 0;
    for (int w = 0; w < wave; ++w) woffs += wtot[w];
    unsigned int incl = inc + woffs;           // inclusive cum over pairs
    unsigned int before = incl - pv;           // cum before this pair
    // locate rank-200 bin (unique thread)
    if (before < 200u && incl >= 200u) {
        unsigned int h0 = hist[2 * t];
        if (before + h0 >= 200u) { Bs = 2 * t; c0s = (int)before; }
        else { Bs = 2 * t + 1; c0s = (int)(before + h0); }
    }
    __syncthreads();
    int B = Bs, c0 = c0s;

    // per-thread: sum d for bins < B; compact boundary bin (int atomic, tiny count)
    float sloc = 0.f;
    for (int i = t; i < nc; i += 256) {
        float d2 = cdl[i];
        int bn = (int)((d2 - dmin2) * binscale);
        bn = bn < 0 ? 0 : (bn > HBINS - 1 ? HBINS - 1 : bn);
        if (bn < B) sloc += sqrtf(fmaxf(d2, 1e-12f));
        else if (bn == B) {
            int p = atomicAdd(&nb, 1);
            if (p < 64) bb[p] = sqrtf(fmaxf(d2, 1e-12f));
        }
    }
#pragma unroll
    for (int o = 32; o >= 1; o >>= 1) sloc += __shfl_xor(sloc, o, 64);
    if (lane == 0) wred[wave] = sloc;
    __syncthreads();

    if (t == 0) {
        float s0 = wred[0] + wred[1] + wred[2] + wred[3];
        int m = nb < 64 ? nb : 64;
        // insertion sort ascending (m is tiny)
        for (int i = 1; i < m; ++i) {
            float v = bb[i]; int j = i - 1;
            while (j >= 0 && bb[j] > v) { bb[j + 1] = bb[j]; --j; }
            bb[j + 1] = v;
        }
        int need = 200 - c0;            // >= 1 by construction
        if (need > m) need = m;         // paranoia guard
        float s199 = s0;                // ranks 0..c0-1
        for (int i = 0; i < need - 1; ++i) s199 += bb[i];   // ranks c0..198
        float d200 = bb[need - 1];      // rank 199
        float w0 = weights[0];
        float cumw = 0.f;               // replicate reference's sequential fp32 cumsum
        for (int i = 0; i < 199; ++i) cumw += w0;
        float TGT = target_w();
        float cost = w0 * s199 + (TGT - cumw) * d200;
        out[row] = 5.0f * expf(-(float)RBW * cost);
    }
}

// ---------------- launch ----------------
extern "C" void kernel_launch(void* const* d_in, const int* in_sizes, int n_in,
                              void* d_out, int out_size, void* d_ws, size_t ws_size,
                              hipStream_t stream) {
    const float* state   = (const float*)d_in[0];
    const float* action  = (const float*)d_in[1];
    const float* experts = (const float*)d_in[2];
    const float* weights = (const float*)d_in[3];
    const float* stdv    = (const float*)d_in[5];
    float* out = (float*)d_out;

    if (ws_size < (size_t)WS_NEEDED) return;

    char* ws = (char*)d_ws;
    _Float16* sd2              = (_Float16*)(ws + OFF_SD2);
    unsigned short* agent_bf16 = (unsigned short*)(ws + OFF_ABF);
    float* b2                  = (float*)(ws + OFF_B2);
    float* thr                 = (float*)(ws + OFF_THR);
    int* cnt2                  = (int*)(ws + OFF_CNT2);
    float* cand2               = (float*)(ws + OFF_CAND2);

    k_agent<<<BATCH, 128, 0, stream>>>(state, action, stdv, agent_bf16, b2, cnt2);
    k_sample<<<SBLK, 256, 0, stream>>>(experts, stdv, agent_bf16, b2, sd2);
    k_tau<<<BATCH, 256, 0, stream>>>(sd2, b2, thr);
    k_compact<<<NBLK, 256, 0, stream>>>(experts, stdv, agent_bf16, thr, b2, cnt2, cand2);
    k_cost<<<BATCH, 256, 0, stream>>>(cand2, cnt2, weights, thr, b2, out);
}